// Round 9
// baseline (184.478 us; speedup 1.0000x reference)
//
#include <hip/hip_runtime.h>
#include <hip/hip_bf16.h>

// Problem constants
#define B_  8
#define S_  2048
#define H_  1024
#define P_  4096
#define K_  2048   // 2*H
#define M_  32768  // B*P

typedef unsigned short u16;
using bf16x8 = __attribute__((ext_vector_type(8))) short;   // 8 bf16 = 4 VGPRs
using f32x4  = __attribute__((ext_vector_type(4))) float;

#define AS1 __attribute__((address_space(1)))
#define AS3 __attribute__((address_space(3)))

__device__ inline u16 f2bf(float f) {
  union { float f; unsigned u; } c; c.f = f;
  unsigned u = c.u;
  unsigned r = (u + 0x7fffu + ((u >> 16) & 1u)) >> 16;  // RNE
  return (u16)r;
}

// ---- prep 1: hidden fp32 -> bf16 ---------------------------------------
__global__ void cvt_hidden_k(const float4* __restrict__ src,
                             ushort4* __restrict__ dst, int n4) {
  int i = blockIdx.x * blockDim.x + threadIdx.x;
  int stride = gridDim.x * blockDim.x;
  for (; i < n4; i += stride) {
    float4 v = src[i];
    ushort4 o;
    o.x = f2bf(v.x); o.y = f2bf(v.y); o.z = f2bf(v.z); o.w = f2bf(v.w);
    dst[i] = o;
  }
}

// ---- prep 2: W1 (K x N fp32, k-major) -> W1T (N x K bf16) ---------------
__global__ void transp_w1_k(const float* __restrict__ w1, u16* __restrict__ w1t) {
  __shared__ float tile[32][33];
  int n0 = blockIdx.x * 32;
  int k0 = blockIdx.y * 32;
  int tx = threadIdx.x;   // 0..31
  int ty = threadIdx.y;   // 0..7
#pragma unroll
  for (int i = 0; i < 32; i += 8)
    tile[ty + i][tx] = w1[(size_t)(k0 + ty + i) * H_ + n0 + tx];
  __syncthreads();
#pragma unroll
  for (int i = 0; i < 32; i += 8)
    w1t[(size_t)(n0 + ty + i) * K_ + k0 + tx] = f2bf(tile[tx][ty + i]);
}

// ---- main fused gather-GEMM + GELU + W2 partial contraction -------------
// Faithful m201 8-phase port. 256x256, BK=64, 8 waves (2M x 4N). LDS =
// 2 dbuf x 4 quadrant-regions x 16KB ([128][64] u16). Each region is read
// in exactly ONE phase into registers that are HELD (reads/phase: 12/4/8/0;
// bva lives ph1->ph4) so regions free progressively mid-tile, legalizing
// stage-into-current-buffer: ph1 stages Aq1(t+1)[d^1], ph2 Aq0(t+2)[d]
// (freed ph1), ph3 Bq0(t+2)[d] (freed ph1), ph4 Bq1(t+2)[d] (freed ph2).
// Single vmcnt(6) at ph4 covers all 4 halves of t+1. Swizzle: 128B rows,
// slot = g ^ (row&7) (conflict-free per 16-lane group), write side via
// pre-swizzled global granule gsrc = (l&7)^((l>>3)&7).
// 512 blocks, XCD-swizzled: each XCD gathers from one batch (4MB = one L2).
__global__ __launch_bounds__(512, 2) void gemm_k(
    const u16*  __restrict__ hidB,   // bf16 hidden [B][S][H]
    const u16*  __restrict__ w1t,    // bf16 W1^T   [N=1024][K=2048]
    const int*  __restrict__ pairs,  // int32 [B][P][2]
    const float* __restrict__ b1,
    const float2* __restrict__ w2,   // W2 rows as float2
    float*      __restrict__ part)   // [16 q][32768 m] float2
{
  __shared__ u16 lds[65536];   // [d][reg: Aq0,Aq1,Bq0,Bq1][8192 u16]

  // XCD-aware bijective swizzle (512 % 8 == 0)
  int orig = blockIdx.x;
  int bid = (orig & 7) * 64 + (orig >> 3);
  int nt = bid & 3;
  int mt = bid >> 2;
  int n0 = nt * 256;
  int m0 = mt * 256;
  int bI = m0 >> 12;       // batch index (256 | 4096)
  int pp = m0 & 4095;

  int t = threadIdx.x;
  int w = t >> 6;          // wave 0..7
  int l = t & 63;
  int lr = l & 15;
  int lj = l >> 4;
  int wr = w >> 2;         // wave row (M): 0..1 -> 128 rows each
  int wn = w & 3;          // wave col (N): 0..3 -> 64 cols each

  // staging row-in-region base and source-granule involution
  int rs   = w * 8 + (l >> 3);           // 0..63
  int gsrc = (l & 7) ^ ((l >> 3) & 7);   // pre-swizzled source granule
  // read-side granule slots (u16 offset): g = kk*4+lj, slot = g ^ (l&7)
  unsigned xo[2];
  xo[0] = (unsigned)(((lj) ^ (l & 7)) * 8);
  xo[1] = (unsigned)(((4 + lj) ^ (l & 7)) * 8);

  // gather indices: sv[i] = pair for tile-row rs + 64*i
  int2 sv[4];
#pragma unroll
  for (int i = 0; i < 4; ++i)
    sv[i] = ((const int2*)pairs)[bI * P_ + pp + rs + 64 * i];

  const u16* hidBase = hidB + ((size_t)bI << 21);  // b * S_*H_

  f32x4 acc[8][4];
#pragma unroll
  for (int i = 0; i < 8; ++i)
#pragma unroll
    for (int j = 0; j < 4; ++j)
      acc[i][j] = (f32x4){0.f, 0.f, 0.f, 0.f};

  // stage A quadrant q of tile T into dbuf d (2 gloads; rows rs, rs+64)
  auto STGA = [&](int d, int q, int T) {
    int k0 = T * 64;
    int kcol = k0 & 1023;
    int half = k0 >> 10;
    int s0 = half ? sv[q].y     : sv[q].x;       // tile-row q*64+rs
    int s1 = half ? sv[q + 2].y : sv[q + 2].x;   // tile-row 128+q*64+rs
    unsigned dst = (unsigned)d * 32768u + (unsigned)q * 8192u +
                   (unsigned)(rs * 64 + (l & 7) * 8);
    __builtin_amdgcn_global_load_lds(
        (const AS1 void*)(hidBase + (((size_t)s0) << 10) + kcol + gsrc * 8),
        (AS3 void*)&lds[dst], 16, 0, 0);
    __builtin_amdgcn_global_load_lds(
        (const AS1 void*)(hidBase + (((size_t)s1) << 10) + kcol + gsrc * 8),
        (AS3 void*)&lds[dst + 4096], 16, 0, 0);
  };
  // stage B quadrant q of tile T into dbuf d (cols interleaved per wn)
  auto STGB = [&](int d, int q, int T) {
    int k0 = T * 64;
    int c0 = ((rs >> 5) * 64) + q * 32 + (rs & 31);
    int c1 = (((rs + 64) >> 5) * 64) + q * 32 + (rs & 31);
    unsigned dst = (unsigned)d * 32768u + (unsigned)(2 + q) * 8192u +
                   (unsigned)(rs * 64 + (l & 7) * 8);
    __builtin_amdgcn_global_load_lds(
        (const AS1 void*)(w1t + (size_t)(n0 + c0) * K_ + k0 + gsrc * 8),
        (AS3 void*)&lds[dst], 16, 0, 0);
    __builtin_amdgcn_global_load_lds(
        (const AS1 void*)(w1t + (size_t)(n0 + c1) * K_ + k0 + gsrc * 8),
        (AS3 void*)&lds[dst + 4096], 16, 0, 0);
  };

#define VM6 asm volatile("s_waitcnt vmcnt(6)" ::: "memory")
#define VM0 asm volatile("s_waitcnt vmcnt(0)" ::: "memory")
#define BAR __builtin_amdgcn_s_barrier()
#define LK0 asm volatile("s_waitcnt lgkmcnt(0)" ::: "memory")
#define LK8 asm volatile("s_waitcnt lgkmcnt(8)" ::: "memory")

// one K-tile = 4 phases (quadrants (0,0),(0,1),(1,1),(1,0)), dbuf D
#define TILE(D, S1, S2, S3, S4, W4)                                           \
  {                                                                           \
    bf16x8 af[2][4], bva[2][2], bvb[2][2];                                    \
    /* ph1: read Aq0(8) + Bq0(4); stage; MFMA (mh0,nh0) */                    \
    _Pragma("unroll") for (int kk = 0; kk < 2; ++kk)                          \
      _Pragma("unroll") for (int mi = 0; mi < 4; ++mi)                        \
        af[kk][mi] = *(const bf16x8*)&lds[(D)*32768u +                        \
            (unsigned)(wr*64 + mi*16 + lr)*64u + xo[kk]];                     \
    _Pragma("unroll") for (int kk = 0; kk < 2; ++kk)                          \
      _Pragma("unroll") for (int ni = 0; ni < 2; ++ni)                        \
        bva[kk][ni] = *(const bf16x8*)&lds[(D)*32768u + 16384u +              \
            (unsigned)(wn*32 + ni*16 + lr)*64u + xo[kk]];                     \
    S1; LK8; BAR; LK0;                                                        \
    __builtin_amdgcn_s_setprio(1);                                            \
    _Pragma("unroll") for (int kk = 0; kk < 2; ++kk)                          \
      _Pragma("unroll") for (int mi = 0; mi < 4; ++mi)                        \
        _Pragma("unroll") for (int ni = 0; ni < 2; ++ni)                      \
          acc[mi][ni] = __builtin_amdgcn_mfma_f32_16x16x32_bf16(              \
              af[kk][mi], bva[kk][ni], acc[mi][ni], 0, 0, 0);                 \
    __builtin_amdgcn_s_setprio(0); BAR;                                       \
    /* ph2: read Bq1(4); stage; MFMA (mh0,nh1) */                             \
    _Pragma("unroll") for (int kk = 0; kk < 2; ++kk)                          \
      _Pragma("unroll") for (int ni = 0; ni < 2; ++ni)                        \
        bvb[kk][ni] = *(const bf16x8*)&lds[(D)*32768u + 24576u +              \
            (unsigned)(wn*32 + ni*16 + lr)*64u + xo[kk]];                     \
    S2; BAR; LK0;                                                             \
    __builtin_amdgcn_s_setprio(1);                                            \
    _Pragma("unroll") for (int kk = 0; kk < 2; ++kk)                          \
      _Pragma("unroll") for (int mi = 0; mi < 4; ++mi)                        \
        _Pragma("unroll") for (int ni = 0; ni < 2; ++ni)                      \
          acc[mi][2 + ni] = __builtin_amdgcn_mfma_f32_16x16x32_bf16(          \
              af[kk][mi], bvb[kk][ni], acc[mi][2 + ni], 0, 0, 0);             \
    __builtin_amdgcn_s_setprio(0); BAR;                                       \
    /* ph3: read Aq1(8) into af; stage; MFMA (mh1,nh1) */                     \
    _Pragma("unroll") for (int kk = 0; kk < 2; ++kk)                          \
      _Pragma("unroll") for (int mi = 0; mi < 4; ++mi)                        \
        af[kk][mi] = *(const bf16x8*)&lds[(D)*32768u + 8192u +                \
            (unsigned)(wr*64 + mi*16 + lr)*64u + xo[kk]];                     \
    S3; BAR; LK0;                                                             \
    __builtin_amdgcn_s_setprio(1);                                            \
    _Pragma("unroll") for (int kk = 0; kk < 2; ++kk)                          \
      _Pragma("unroll") for (int mi = 0; mi < 4; ++mi)                        \
        _Pragma("unroll") for (int ni = 0; ni < 2; ++ni)                      \
          acc[4 + mi][2 + ni] = __builtin_amdgcn_mfma_f32_16x16x32_bf16(      \
              af[kk][mi], bvb[kk][ni], acc[4 + mi][2 + ni], 0, 0, 0);         \
    __builtin_amdgcn_s_setprio(0); BAR;                                       \
    /* ph4: no reads; stage; counted wait; MFMA (mh1,nh0) w/ held bva */      \
    S4; W4; BAR;                                                              \
    __builtin_amdgcn_s_setprio(1);                                            \
    _Pragma("unroll") for (int kk = 0; kk < 2; ++kk)                          \
      _Pragma("unroll") for (int mi = 0; mi < 4; ++mi)                        \
        _Pragma("unroll") for (int ni = 0; ni < 2; ++ni)                      \
          acc[4 + mi][ni] = __builtin_amdgcn_mfma_f32_16x16x32_bf16(          \
              af[kk][mi], bva[kk][ni], acc[4 + mi][ni], 0, 0, 0);             \
    __builtin_amdgcn_s_setprio(0); BAR;                                       \
  }

  // ---- prologue: t0 all 4 halves, t1 first 3; vmcnt(6) -> t0 ready ----
  STGA(0, 0, 0); STGB(0, 0, 0); STGB(0, 1, 0); STGA(0, 1, 0);
  STGA(1, 0, 1); STGB(1, 0, 1); STGB(1, 1, 1);
  VM6;
  BAR;

  // ---- main loop: tiles 0..29 ----
  for (int u = 0; u < 15; ++u) {
    int T0 = 2 * u, T1 = 2 * u + 1;
    TILE(0, STGA(1, 1, T0 + 1), STGA(0, 0, T0 + 2), STGB(0, 0, T0 + 2),
            STGB(0, 1, T0 + 2), VM6);
    TILE(1, STGA(0, 1, T1 + 1), STGA(1, 0, T1 + 2), STGB(1, 0, T1 + 2),
            STGB(1, 1, T1 + 2), VM6);
  }
  // ---- tail: tile 30 (stage last half of 31, drain), tile 31 ----
  TILE(0, STGA(1, 1, 31), , , , VM0);
  TILE(1, , , , , );
#undef TILE

  // ---- fused epilogue: bias + exact GELU + W2 contraction ----
  // acc element (mi,ni,j): row = wr*128+mi*16+lj*4+j, col = wn*64+ni*16+lr
  int q = nt * 4 + wn;
  float2* pOut = (float2*)part;
#pragma unroll
  for (int mi = 0; mi < 8; ++mi) {
    float s0[4] = {0.f, 0.f, 0.f, 0.f};
    float s1[4] = {0.f, 0.f, 0.f, 0.f};
#pragma unroll
    for (int ni = 0; ni < 4; ++ni) {
      int n = n0 + wn * 64 + ni * 16 + lr;
      float bb = b1[n];
      float2 wv = w2[n];
#pragma unroll
      for (int j = 0; j < 4; ++j) {
        float x = acc[mi][ni][j] + bb;
        float g = 0.5f * x * (1.0f + erff(x * 0.70710678118654752f));
        s0[j] += g * wv.x;
        s1[j] += g * wv.y;
      }
    }
#pragma unroll
    for (int off = 1; off < 16; off <<= 1) {
#pragma unroll
      for (int j = 0; j < 4; ++j) {
        s0[j] += __shfl_xor(s0[j], off, 64);
        s1[j] += __shfl_xor(s1[j], off, 64);
      }
    }
    if (lr == 0) {
#pragma unroll
      for (int j = 0; j < 4; ++j) {
        int m = m0 + wr * 128 + mi * 16 + lj * 4 + j;
        pOut[((size_t)q << 15) + m] = make_float2(s0[j], s1[j]);
      }
    }
  }
}

// ---- final reduce over 16 partials + b2 ---------------------------------
__global__ void reduce_k(const float2* __restrict__ part,
                         const float* __restrict__ b2,
                         float2* __restrict__ out) {
  int m = blockIdx.x * blockDim.x + threadIdx.x;
  if (m >= M_) return;
  float a0 = b2[0], a1 = b2[1];
#pragma unroll
  for (int q = 0; q < 16; ++q) {
    float2 v = part[((size_t)q << 15) + m];
    a0 += v.x; a1 += v.y;
  }
  out[m] = make_float2(a0, a1);
}

extern "C" void kernel_launch(void* const* d_in, const int* in_sizes, int n_in,
                              void* d_out, int out_size, void* d_ws, size_t ws_size,
                              hipStream_t stream) {
  const float* hidden = (const float*)d_in[0];
  const int*   pairs  = (const int*)d_in[1];
  const float* W1     = (const float*)d_in[2];
  const float* b1     = (const float*)d_in[3];
  const float* W2     = (const float*)d_in[4];
  const float* b2     = (const float*)d_in[5];
  float* out = (float*)d_out;

  // ws layout: hidden_bf16 (32 MiB) | W1T_bf16 (4 MiB) | partials (4 MiB)
  u16* hidB = (u16*)d_ws;
  u16* w1t  = hidB + (size_t)B_ * S_ * H_;
  float* part = (float*)(w1t + (size_t)H_ * K_);

  int n4 = (B_ * S_ * H_) / 4;
  cvt_hidden_k<<<4096, 256, 0, stream>>>((const float4*)hidden, (ushort4*)hidB, n4);
  transp_w1_k<<<dim3(H_ / 32, K_ / 32), dim3(32, 8), 0, stream>>>(W1, w1t);
  gemm_k<<<(M_ / 256) * (H_ / 256), 512, 0, stream>>>(
      hidB, w1t, pairs, b1, (const float2*)W2, part);
  reduce_k<<<(M_ + 255) / 256, 256, 0, stream>>>(
      (const float2*)part, b2, (float2*)out);
}

// Round 10
// 178.780 us; speedup vs baseline: 1.0319x; 1.0319x over previous
//
#include <hip/hip_runtime.h>
#include <hip/hip_bf16.h>

// Problem constants
#define B_  8
#define S_  2048
#define H_  1024
#define P_  4096
#define K_  2048   // 2*H
#define M_  32768  // B*P
#define NT_ 32     // K-tiles (BK=64)

typedef unsigned short u16;
using bf16x8 = __attribute__((ext_vector_type(8))) short;   // 8 bf16 = 4 VGPRs
using f32x4  = __attribute__((ext_vector_type(4))) float;

#define AS1 __attribute__((address_space(1)))
#define AS3 __attribute__((address_space(3)))

__device__ inline u16 f2bf(float f) {
  union { float f; unsigned u; } c; c.f = f;
  unsigned u = c.u;
  unsigned r = (u + 0x7fffu + ((u >> 16) & 1u)) >> 16;  // RNE
  return (u16)r;
}

// ---- prep 1: hidden fp32 -> bf16 ---------------------------------------
__global__ void cvt_hidden_k(const float4* __restrict__ src,
                             ushort4* __restrict__ dst, int n4) {
  int i = blockIdx.x * blockDim.x + threadIdx.x;
  int stride = gridDim.x * blockDim.x;
  for (; i < n4; i += stride) {
    float4 v = src[i];
    ushort4 o;
    o.x = f2bf(v.x); o.y = f2bf(v.y); o.z = f2bf(v.z); o.w = f2bf(v.w);
    dst[i] = o;
  }
}

// ---- prep 2: W1 (K x N fp32, k-major) -> W1T (N x K bf16) ---------------
__global__ void transp_w1_k(const float* __restrict__ w1, u16* __restrict__ w1t) {
  __shared__ float tile[32][33];
  int n0 = blockIdx.x * 32;
  int k0 = blockIdx.y * 32;
  int tx = threadIdx.x;   // 0..31
  int ty = threadIdx.y;   // 0..7
#pragma unroll
  for (int i = 0; i < 32; i += 8)
    tile[ty + i][tx] = w1[(size_t)(k0 + ty + i) * H_ + n0 + tx];
  __syncthreads();
#pragma unroll
  for (int i = 0; i < 32; i += 8)
    w1t[(size_t)(n0 + ty + i) * K_ + k0 + tx] = f2bf(tile[tx][ty + i]);
}

// ---- main fused gather-GEMM + GELU + W2 partial contraction -------------
// TLP structure: 128x128 tile, BK=64, 256 threads (4 waves, 2M x 2N),
// double-buffered LDS = 64KB -> 2 BLOCKS PER CU. Per block: simple R2-style
// loop {stage t+1 into other buf | 16 frag ds_reads | 32 MFMA/wave |
// syncthreads}. The per-block drain stall is covered by the co-resident
// block's MFMA cluster (m114 cross-block pipe overlap) instead of intra-
// block schedule asymmetry. grid = 2048, XCD-swizzled (2048%8==0): each
// XCD's 256 blocks = 32 M-tiles x 8 N-tiles = exactly one batch (gather
// working set 4MB = one L2).
__global__ __launch_bounds__(256, 2) void gemm_k(
    const u16*  __restrict__ hidB,   // bf16 hidden [B][S][H]
    const u16*  __restrict__ w1t,    // bf16 W1^T   [N=1024][K=2048]
    const int*  __restrict__ pairs,  // int32 [B][P][2]
    const float* __restrict__ b1,
    const float2* __restrict__ w2,   // W2 rows as float2
    float*      __restrict__ part)   // [16 q][32768 m] float2
{
  __shared__ u16 lds[2][16384];   // per buf: A [128][64] | B [128][64] = 32KB

  // XCD-aware bijective swizzle (2048 % 8 == 0): 256 consecutive per XCD
  int orig = blockIdx.x;
  int bid = (orig & 7) * 256 + (orig >> 3);
  int nt = bid & 7;        // 8 N-tiles of 128
  int mt = bid >> 3;       // 256 M-tiles of 128
  int n0 = nt * 128;
  int m0 = mt * 128;
  int bI = m0 >> 12;       // batch index (per XCD: mt>>5 == xcd's batch)
  int pp = m0 & 4095;

  int t = threadIdx.x;     // 0..255
  int w = t >> 6;          // wave 0..3
  int l = t & 63;
  int lr = l & 15;
  int lj = l >> 4;
  int wr = w >> 1;         // wave row (M): 0..1 -> 64 rows each
  int wn = w & 1;          // wave col (N): 0..1 -> 64 cols each

  // staging source granule involution (write side of read-slot XOR)
  int gsrc = (l & 7) ^ ((l >> 3) & 7);
  // read-side granule slots (u16 offset): g = kk*4+lj, slot = g ^ (lr&7)
  unsigned xo[2];
  xo[0] = (unsigned)(((lj) ^ (l & 7)) * 8);
  xo[1] = (unsigned)(((4 + lj) ^ (l & 7)) * 8);

  // gather indices for staged rows r_i = i*32 + (t>>3)
  int2 sv[4];
#pragma unroll
  for (int i = 0; i < 4; ++i)
    sv[i] = ((const int2*)pairs)[bI * P_ + pp + i * 32 + (t >> 3)];

  const u16* hidBase = hidB + ((size_t)bI << 21);  // b * S_*H_

  f32x4 acc[4][4];
#pragma unroll
  for (int i = 0; i < 4; ++i)
#pragma unroll
    for (int j = 0; j < 4; ++j)
      acc[i][j] = (f32x4){0.f, 0.f, 0.f, 0.f};

  // stage K-tile T into buf: 4 A gloads + 4 B gloads (16B each)
  auto STAGE = [&](int buf, int T) {
    int k0 = T * 64;
    int kcol = k0 & 1023;     // column within selected half-row
    int half = k0 >> 10;      // 0 -> emb1, 1 -> emb2
    unsigned dbase = (unsigned)buf * 16384u + (unsigned)t * 8u;
#pragma unroll
    for (int i = 0; i < 4; ++i) {
      int s = half ? sv[i].y : sv[i].x;
      __builtin_amdgcn_global_load_lds(
          (const AS1 void*)(hidBase + (((size_t)s) << 10) + kcol + gsrc * 8),
          (AS3 void*)&lds[0][dbase + (unsigned)i * 2048u], 16, 0, 0);
    }
    int r = t >> 3;           // 0..31
#pragma unroll
    for (int i = 0; i < 4; ++i) {
      __builtin_amdgcn_global_load_lds(
          (const AS1 void*)(w1t + (size_t)(n0 + i * 32 + r) * K_ + k0 + gsrc * 8),
          (AS3 void*)&lds[0][dbase + 8192u + (unsigned)i * 2048u], 16, 0, 0);
    }
  };

  // prologue
  STAGE(0, 0);
  __syncthreads();

  for (int T = 0; T < NT_; ++T) {
    int cur = T & 1;
    if (T + 1 < NT_) STAGE(cur ^ 1, T + 1);

    bf16x8 af[2][4], bv[2][4];
#pragma unroll
    for (int kk = 0; kk < 2; ++kk) {
#pragma unroll
      for (int mi = 0; mi < 4; ++mi)
        af[kk][mi] = *(const bf16x8*)&lds[cur][
            (unsigned)(wr * 64 + mi * 16 + lr) * 64u + xo[kk]];
#pragma unroll
      for (int ni = 0; ni < 4; ++ni)
        bv[kk][ni] = *(const bf16x8*)&lds[cur][8192u +
            (unsigned)(wn * 64 + ni * 16 + lr) * 64u + xo[kk]];
    }
    __builtin_amdgcn_s_setprio(1);
#pragma unroll
    for (int kk = 0; kk < 2; ++kk)
#pragma unroll
      for (int mi = 0; mi < 4; ++mi)
#pragma unroll
        for (int ni = 0; ni < 4; ++ni)
          acc[mi][ni] = __builtin_amdgcn_mfma_f32_16x16x32_bf16(
              af[kk][mi], bv[kk][ni], acc[mi][ni], 0, 0, 0);
    __builtin_amdgcn_s_setprio(0);
    __syncthreads();   // vmcnt(0)+lgkm drain + barrier; TLP covers the stall
  }

  // ---- fused epilogue: bias + exact GELU + W2 contraction ----
  // acc element (mi,ni,j): row = wr*64+mi*16+lj*4+j, col = wn*64+ni*16+lr
  int q = nt * 2 + wn;
  float2* pOut = (float2*)part;
#pragma unroll
  for (int mi = 0; mi < 4; ++mi) {
    float s0[4] = {0.f, 0.f, 0.f, 0.f};
    float s1[4] = {0.f, 0.f, 0.f, 0.f};
#pragma unroll
    for (int ni = 0; ni < 4; ++ni) {
      int n = n0 + wn * 64 + ni * 16 + lr;
      float bb = b1[n];
      float2 wv = w2[n];
#pragma unroll
      for (int j = 0; j < 4; ++j) {
        float x = acc[mi][ni][j] + bb;
        float g = 0.5f * x * (1.0f + erff(x * 0.70710678118654752f));
        s0[j] += g * wv.x;
        s1[j] += g * wv.y;
      }
    }
#pragma unroll
    for (int off = 1; off < 16; off <<= 1) {
#pragma unroll
      for (int j = 0; j < 4; ++j) {
        s0[j] += __shfl_xor(s0[j], off, 64);
        s1[j] += __shfl_xor(s1[j], off, 64);
      }
    }
    if (lr == 0) {
#pragma unroll
      for (int j = 0; j < 4; ++j) {
        int m = m0 + wr * 64 + mi * 16 + lj * 4 + j;
        pOut[((size_t)q << 15) + m] = make_float2(s0[j], s1[j]);
      }
    }
  }
}

// ---- final reduce over 16 partials + b2 ---------------------------------
__global__ void reduce_k(const float2* __restrict__ part,
                         const float* __restrict__ b2,
                         float2* __restrict__ out) {
  int m = blockIdx.x * blockDim.x + threadIdx.x;
  if (m >= M_) return;
  float a0 = b2[0], a1 = b2[1];
#pragma unroll
  for (int q = 0; q < 16; ++q) {
    float2 v = part[((size_t)q << 15) + m];
    a0 += v.x; a1 += v.y;
  }
  out[m] = make_float2(a0, a1);
}

extern "C" void kernel_launch(void* const* d_in, const int* in_sizes, int n_in,
                              void* d_out, int out_size, void* d_ws, size_t ws_size,
                              hipStream_t stream) {
  const float* hidden = (const float*)d_in[0];
  const int*   pairs  = (const int*)d_in[1];
  const float* W1     = (const float*)d_in[2];
  const float* b1     = (const float*)d_in[3];
  const float* W2     = (const float*)d_in[4];
  const float* b2     = (const float*)d_in[5];
  float* out = (float*)d_out;

  // ws layout: hidden_bf16 (32 MiB) | W1T_bf16 (4 MiB) | partials (4 MiB)
  u16* hidB = (u16*)d_ws;
  u16* w1t  = hidB + (size_t)B_ * S_ * H_;
  float* part = (float*)(w1t + (size_t)H_ * K_);

  int n4 = (B_ * S_ * H_) / 4;
  cvt_hidden_k<<<4096, 256, 0, stream>>>((const float4*)hidden, (ushort4*)hidB, n4);
  transp_w1_k<<<dim3(H_ / 32, K_ / 32), dim3(32, 8), 0, stream>>>(W1, w1t);
  gemm_k<<<(M_ / 128) * (H_ / 128), 256, 0, stream>>>(
      hidB, w1t, pairs, b1, (const float2*)W2, part);
  reduce_k<<<(M_ + 255) / 256, 256, 0, stream>>>(
      (const float2*)part, b2, (float2*)out);
}